// Round 2
// baseline (258.704 us; speedup 1.0000x reference)
//
#include <hip/hip_runtime.h>
#include <math.h>

#define HIDDEN 1024
#define NL 9
#define LEAN_TAU 0.25f
#define LEAN_DELTA 0.35f

// ---------------- Kernel 1: emission logits + lean adjust ----------------
// One wave per token (4 waves/block). emis_w staged in LDS (36 KB).
__global__ __launch_bounds__(256) void logits_k(
    const float* __restrict__ hs, const float* __restrict__ w,
    const float* __restrict__ bias, const int* __restrict__ amask,
    float* __restrict__ e, int B, int T) {
  __shared__ float lw[NL * HIDDEN];
  const int TOK = T - 2;
  for (int i = threadIdx.x; i < NL * HIDDEN / 4; i += blockDim.x)
    reinterpret_cast<float4*>(lw)[i] = reinterpret_cast<const float4*>(w)[i];
  __syncthreads();
  const int wave = threadIdx.x >> 6, lane = threadIdx.x & 63;
  const int nTok = B * TOK;
  float bb9[NL];
#pragma unroll
  for (int l = 0; l < NL; ++l) bb9[l] = bias[l];
  for (int tok = blockIdx.x * 4 + wave; tok < nTok; tok += gridDim.x * 4) {
    const int b = tok / TOK, t = tok % TOK;
    const float4* hrow =
        reinterpret_cast<const float4*>(hs + ((size_t)b * T + t + 1) * HIDDEN);
    float acc[NL];
#pragma unroll
    for (int l = 0; l < NL; ++l) acc[l] = 0.f;
#pragma unroll
    for (int k = 0; k < 4; ++k) {
      const int h4 = lane + 64 * k;  // float4 index into the 1024-long row
      const float4 hv = hrow[h4];
#pragma unroll
      for (int l = 0; l < NL; ++l) {
        const float4 wv = reinterpret_cast<const float4*>(lw + l * HIDDEN)[h4];
        acc[l] = fmaf(hv.x, wv.x,
                 fmaf(hv.y, wv.y, fmaf(hv.z, wv.z, fmaf(hv.w, wv.w, acc[l]))));
      }
    }
    // full-wave butterfly reduce each of the 9 accumulators
#pragma unroll
    for (int l = 0; l < NL; ++l) {
      float v = acc[l];
#pragma unroll
      for (int off = 32; off; off >>= 1) v += __shfl_xor(v, off);
      acc[l] = v + bb9[l];
    }
    // top-2 over 9 labels (pre-adjust values, == stop_gradient view)
    float m1 = -INFINITY, m2 = -INFINITY;
#pragma unroll
    for (int l = 0; l < NL; ++l) {
      const float v = acc[l];
      if (v > m1) { m2 = m1; m1 = v; }
      else if (v > m2) { m2 = v; }
    }
    const bool unc = (m1 - m2 < LEAN_TAU) && (amask[b * T + t + 1] != 0);
    if (unc) acc[0] += LEAN_DELTA;
    if (lane < NL) {
      float outv = acc[0];
#pragma unroll
      for (int l = 1; l < NL; ++l)
        if (lane == l) outv = acc[l];
      e[(size_t)tok * NL + lane] = outv;
    }
  }
}

// ---------------- Kernel 2: per-batch CRF scan (num + den) ----------------
// One wave per batch. Lane j (j<9) holds alpha_j and trans[:,j] in registers.
__global__ __launch_bounds__(64) void crf_k(
    const float* __restrict__ e, const int* __restrict__ labels,
    const float* __restrict__ start_t, const float* __restrict__ end_t,
    const float* __restrict__ trans, float* __restrict__ llh, int B, int T) {
  const int TOK = T - 2;
  const int b = blockIdx.x;
  const int lane = threadIdx.x;
  const float* eb = e + (size_t)b * TOK * NL;
  const int* lb = labels + (size_t)b * T + 1;  // gold[t] for t in [0,TOK)

  float tr[NL];  // trans[i][lane] for i=0..8 (column `lane`)
#pragma unroll
  for (int i = 0; i < NL; ++i) tr[i] = (lane < NL) ? trans[i * NL + lane] : 0.f;

  // t = 0 (unmasked, per torchcrf semantics mirrored by the reference)
  const int g0 = lb[0];
  int tg = (g0 == -100) ? 0 : g0;
  float score = start_t[tg] + eb[tg];
  int last = tg, prev = tg;
  float alpha = (lane < NL) ? (start_t[lane] + eb[lane]) : -INFINITY;

  for (int t = 1; t < TOK; ++t) {
    const float* et = eb + t * NL;
    const int g = lb[t];
    const int cur = (g == -100) ? 0 : g;
    const bool mt = (g != -100);  // CRF mask comes from labels, not attention
    if (mt) {
      score += trans[prev * NL + cur] + et[cur];
      last = cur;
    }
    prev = cur;  // prev tag advances regardless of mask (matches reference)

    const float ev = (lane < NL) ? et[lane] : 0.f;
    float s[NL], mx = -INFINITY;
#pragma unroll
    for (int i = 0; i < NL; ++i) {
      const float ai = __shfl(alpha, i);
      s[i] = ai + tr[i];
      mx = fmaxf(mx, s[i]);
    }
    float sum = 0.f;
#pragma unroll
    for (int i = 0; i < NL; ++i) sum += __expf(s[i] - mx);
    const float nxt = mx + __logf(sum) + ev;
    if (mt) alpha = (lane < NL) ? nxt : -INFINITY;
  }

  const float num = score + end_t[last];
  // den = logsumexp over lanes j<9 of (alpha_j + end_t[j])
  const float v = (lane < NL) ? (alpha + end_t[lane]) : -INFINITY;
  float mx = v;
#pragma unroll
  for (int off = 32; off; off >>= 1) mx = fmaxf(mx, __shfl_xor(mx, off));
  float sum = (lane < NL) ? __expf(v - mx) : 0.f;
#pragma unroll
  for (int off = 32; off; off >>= 1) sum += __shfl_xor(sum, off);
  const float den = mx + __logf(sum);
  if (lane == 0) llh[b] = num - den;
}

// ---------------- Kernel 3: -mean(llh) ----------------
__global__ __launch_bounds__(64) void reduce_k(const float* __restrict__ llh,
                                               float* __restrict__ out, int B) {
  float v = 0.f;
  for (int i = threadIdx.x; i < B; i += 64) v += llh[i];
#pragma unroll
  for (int off = 32; off; off >>= 1) v += __shfl_xor(v, off);
  if (threadIdx.x == 0) out[0] = -v / (float)B;
}

extern "C" void kernel_launch(void* const* d_in, const int* in_sizes, int n_in,
                              void* d_out, int out_size, void* d_ws,
                              size_t ws_size, hipStream_t stream) {
  const float* hs     = (const float*)d_in[0];
  const float* w      = (const float*)d_in[1];
  const float* bias   = (const float*)d_in[2];
  const float* st     = (const float*)d_in[3];
  const float* et     = (const float*)d_in[4];
  const float* tr     = (const float*)d_in[5];
  const int*   amask  = (const int*)d_in[6];
  const int*   labels = (const int*)d_in[7];

  const int T = 512;                 // per reference setup
  const int B = in_sizes[6] / T;     // attention_mask is (B, T)
  const int TOK = T - 2;

  float* e   = (float*)d_ws;                       // (B, TOK, 9) adjusted logits
  float* llh = e + (size_t)B * TOK * NL;           // (B,)

  const int nTok = B * TOK;
  int grid1 = (nTok + 3) / 4;
  if (grid1 > 2048) grid1 = 2048;
  logits_k<<<grid1, 256, 0, stream>>>(hs, w, bias, amask, e, B, T);
  crf_k<<<B, 64, 0, stream>>>(e, labels, st, et, tr, llh, B, T);
  reduce_k<<<1, 64, 0, stream>>>(llh, (float*)d_out, B);
}

// Round 4
// 98.705 us; speedup vs baseline: 2.6210x; 2.6210x over previous
//
#include <hip/hip_runtime.h>
#include <math.h>

#define HIDDEN 1024
#define NL 9
#define LEAN_TAU 0.25f
#define LEAN_DELTA 0.35f
#define LCH 16  // CRF scan chunk length

// ---------------- Kernel 1: emission logits + lean adjust ----------------
__global__ __launch_bounds__(256) void logits_k(
    const float* __restrict__ hs, const float* __restrict__ w,
    const float* __restrict__ bias, const int* __restrict__ amask,
    float* __restrict__ e, int B, int T) {
  __shared__ float lw[NL * HIDDEN];
  const int TOK = T - 2;
  for (int i = threadIdx.x; i < NL * HIDDEN / 4; i += blockDim.x)
    reinterpret_cast<float4*>(lw)[i] = reinterpret_cast<const float4*>(w)[i];
  __syncthreads();
  const int wave = threadIdx.x >> 6, lane = threadIdx.x & 63;
  const int nTok = B * TOK;
  float bb9[NL];
#pragma unroll
  for (int l = 0; l < NL; ++l) bb9[l] = bias[l];
  for (int tok = blockIdx.x * 4 + wave; tok < nTok; tok += gridDim.x * 4) {
    const int b = tok / TOK, t = tok % TOK;
    const float4* hrow =
        reinterpret_cast<const float4*>(hs + ((size_t)b * T + t + 1) * HIDDEN);
    float acc[NL];
#pragma unroll
    for (int l = 0; l < NL; ++l) acc[l] = 0.f;
#pragma unroll
    for (int k = 0; k < 4; ++k) {
      const int h4 = lane + 64 * k;
      const float4 hv = hrow[h4];
#pragma unroll
      for (int l = 0; l < NL; ++l) {
        const float4 wv = reinterpret_cast<const float4*>(lw + l * HIDDEN)[h4];
        acc[l] = fmaf(hv.x, wv.x,
                 fmaf(hv.y, wv.y, fmaf(hv.z, wv.z, fmaf(hv.w, wv.w, acc[l]))));
      }
    }
#pragma unroll
    for (int l = 0; l < NL; ++l) {
      float v = acc[l];
#pragma unroll
      for (int off = 32; off; off >>= 1) v += __shfl_xor(v, off);
      acc[l] = v + bb9[l];
    }
    float m1 = -INFINITY, m2 = -INFINITY;
#pragma unroll
    for (int l = 0; l < NL; ++l) {
      const float v = acc[l];
      if (v > m1) { m2 = m1; m1 = v; }
      else if (v > m2) { m2 = v; }
    }
    const bool unc = (m1 - m2 < LEAN_TAU) && (amask[b * T + t + 1] != 0);
    if (unc) acc[0] += LEAN_DELTA;
    if (lane < NL) {
      float outv = acc[0];
#pragma unroll
      for (int l = 1; l < NL; ++l)
        if (lane == l) outv = acc[l];
      e[(size_t)tok * NL + lane] = outv;
    }
  }
}

// ---------------- Kernel 2: per-chunk log-space matrix products ----------------
// 7 chunks per wave; lane = sub*9 + i holds row i of chunk sub's 9x9 product.
// Zero cross-lane traffic in the hot loop; trans broadcast via LDS.
__global__ __launch_bounds__(64) void chunk_k(
    const float* __restrict__ e, const int* __restrict__ labels,
    const float* __restrict__ trans, float* __restrict__ Pout,
    int B, int T, int C) {
  const int TOK = T - 2;
  __shared__ float e2[7][LCH][NL];
  __shared__ float tr2[NL * NL];
  __shared__ int msk[7][LCH];
  const int tid = threadIdx.x;
  const int nG = B * C;
  const int gbase = blockIdx.x * 7;

  for (int idx = tid; idx < NL * NL; idx += 64) tr2[idx] = trans[idx];
  for (int idx = tid; idx < 7 * LCH * NL; idx += 64) {
    const int sub = idx / (LCH * NL), rem = idx % (LCH * NL);
    const int step = rem / NL, j = rem % NL;
    const int g = gbase + sub;
    if (g < nG) {
      const int b = g / C, c = g % C;
      const int t = 1 + c * LCH + step;
      if (t < TOK) e2[sub][step][j] = e[((size_t)b * TOK + t) * NL + j];
    }
  }
  for (int idx = tid; idx < 7 * LCH; idx += 64) {
    const int sub = idx / LCH, step = idx % LCH;
    const int g = gbase + sub;
    if (g < nG) {
      const int b = g / C, c = g % C;
      const int t = 1 + c * LCH + step;
      msk[sub][step] = (t < TOK) ? (labels[(size_t)b * T + 1 + t] != -100) : 0;
    }
  }
  __syncthreads();

  const int sub = tid / NL, i = tid % NL;  // sub==7 only for tid 63 (inactive)
  const int g = gbase + sub;
  const bool act = (sub < 7) && (g < nG);
  int len = 1;
  if (act) { const int c = g % C; len = min(LCH, TOK - (1 + c * LCH)); }

  float P[NL];
  {
    const int m0 = act ? msk[sub][0] : 0;
#pragma unroll
    for (int j = 0; j < NL; ++j)
      P[j] = m0 ? (tr2[i * NL + j] + e2[sub][0][j])
                : ((i == j) ? 0.f : -1e30f);
  }
  for (int step = 1; step < LCH; ++step) {
    if (step >= len) break;
    const int mt = msk[sub][step];
    float Pn[NL];
#pragma unroll
    for (int j = 0; j < NL; ++j) {
      float s[NL];
      s[0] = P[0] + tr2[0 * NL + j];
      float mx = s[0];
#pragma unroll
      for (int k = 1; k < NL; ++k) {
        s[k] = P[k] + tr2[k * NL + j];
        mx = fmaxf(mx, s[k]);
      }
      float sum = 0.f;
#pragma unroll
      for (int k = 0; k < NL; ++k) sum += __expf(s[k] - mx);
      Pn[j] = mx + __logf(sum) + e2[sub][step][j];
    }
#pragma unroll
    for (int j = 0; j < NL; ++j) P[j] = mt ? Pn[j] : P[j];
  }
  if (act) {
    float* dst = Pout + (size_t)g * 81 + i * NL;
#pragma unroll
    for (int j = 0; j < NL; ++j) dst[j] = P[j];
  }
}

// ---------------- Kernel 3: per-batch combine (num + den fold) ----------------
__global__ __launch_bounds__(64) void combine_k(
    const float* __restrict__ e, const int* __restrict__ labels,
    const float* __restrict__ start_t, const float* __restrict__ end_t,
    const float* __restrict__ trans, const float* __restrict__ Pmat,
    float* __restrict__ llh, int B, int T, int C) {
  const int TOK = T - 2;
  const int b = blockIdx.x, lane = threadIdx.x;
  const float* eb = e + (size_t)b * TOK * NL;
  const int* lb = labels + (size_t)b * T + 1;

  // ---- numerator: chain-free, data-parallel over t ----
  const int g0r = lb[0];
  const int tg0 = (g0r == -100) ? 0 : g0r;
  float nsum = 0.f;
  int pack = -1;  // (t<<4)|tag of last masked step
  for (int t = 1 + lane; t < TOK; t += 64) {
    const int gr = lb[t], pr = lb[t - 1];
    if (gr != -100) {
      const int cur = gr;
      const int prev = (pr == -100) ? 0 : pr;
      nsum += trans[prev * NL + cur] + eb[t * NL + cur];
      pack = (t << 4) | cur;
    }
  }
#pragma unroll
  for (int off = 32; off; off >>= 1) {
    nsum += __shfl_xor(nsum, off);
    pack = max(pack, __shfl_xor(pack, off));
  }
  const int last = (pack < 0) ? tg0 : (pack & 15);
  const float num = start_t[tg0] + eb[tg0] + nsum + end_t[last];

  // ---- denominator: fold C chunk matrices ----
  float alpha = (lane < NL) ? (start_t[lane] + eb[lane]) : -1e30f;
  for (int c = 0; c < C; ++c) {
    const float* Pc = Pmat + ((size_t)b * C + c) * 81;
    float col[NL];
#pragma unroll
    for (int i = 0; i < NL; ++i)
      col[i] = (lane < NL) ? Pc[i * NL + lane] : -1e30f;
    float s[NL];
    float mx = -1e30f;
#pragma unroll
    for (int i = 0; i < NL; ++i) {
      const float ai = __shfl(alpha, i);
      s[i] = ai + col[i];
      mx = fmaxf(mx, s[i]);
    }
    float sum = 0.f;
#pragma unroll
    for (int i = 0; i < NL; ++i) sum += __expf(s[i] - mx);
    const float nx = mx + __logf(sum);
    alpha = (lane < NL) ? nx : -1e30f;
  }
  const float v = (lane < NL) ? (alpha + end_t[lane]) : -1e30f;
  float mx = v;
#pragma unroll
  for (int off = 32; off; off >>= 1) mx = fmaxf(mx, __shfl_xor(mx, off));
  float sum = (lane < NL) ? __expf(v - mx) : 0.f;
#pragma unroll
  for (int off = 32; off; off >>= 1) sum += __shfl_xor(sum, off);
  const float den = mx + __logf(sum);
  if (lane == 0) llh[b] = num - den;
}

// ---------------- Kernel 4: -mean(llh) ----------------
__global__ __launch_bounds__(64) void reduce_k(const float* __restrict__ llh,
                                               float* __restrict__ out, int B) {
  float v = 0.f;
  for (int i = threadIdx.x; i < B; i += 64) v += llh[i];
#pragma unroll
  for (int off = 32; off; off >>= 1) v += __shfl_xor(v, off);
  if (threadIdx.x == 0) out[0] = -v / (float)B;
}

extern "C" void kernel_launch(void* const* d_in, const int* in_sizes, int n_in,
                              void* d_out, int out_size, void* d_ws,
                              size_t ws_size, hipStream_t stream) {
  const float* hs     = (const float*)d_in[0];
  const float* w      = (const float*)d_in[1];
  const float* bias   = (const float*)d_in[2];
  const float* st     = (const float*)d_in[3];
  const float* et     = (const float*)d_in[4];
  const float* tr     = (const float*)d_in[5];
  const int*   amask  = (const int*)d_in[6];
  const int*   labels = (const int*)d_in[7];

  const int T = 512;
  const int B = in_sizes[6] / T;
  const int TOK = T - 2;
  const int C = (TOK - 1 + LCH - 1) / LCH;  // chunks of the 509 recurrence steps

  float* e    = (float*)d_ws;                 // (B, TOK, 9)
  float* llh  = e + (size_t)B * TOK * NL;     // (B,)
  float* Pmat = llh + B;                      // (B*C, 81)

  const int nTok = B * TOK;
  int grid1 = (nTok + 3) / 4;
  if (grid1 > 2048) grid1 = 2048;
  logits_k<<<grid1, 256, 0, stream>>>(hs, w, bias, amask, e, B, T);
  const int nG = B * C;
  chunk_k<<<(nG + 6) / 7, 64, 0, stream>>>(e, labels, tr, Pmat, B, T, C);
  combine_k<<<B, 64, 0, stream>>>(e, labels, st, et, tr, Pmat, llh, B, T, C);
  reduce_k<<<1, 64, 0, stream>>>(llh, (float*)d_out, B);
}